// Round 2
// baseline (213.215 us; speedup 1.0000x reference)
//
#include <hip/hip_runtime.h>
#include <stdint.h>

#define SQ 2048
#define DH 128
#define SCALER 0.08838834764831845f  // 1/sqrt(128)

typedef float f32x4 __attribute__((ext_vector_type(4)));
typedef short s16x8 __attribute__((ext_vector_type(8)));

__device__ __forceinline__ short f2bf(float f) {
  uint32_t x = __float_as_uint(f);
  uint32_t r = (x + 0x7fffu + ((x >> 16) & 1u)) >> 16;  // RNE
  return (short)(r & 0xffffu);
}

__device__ __forceinline__ void mfma16(f32x4& d, s16x8 a, s16x8 b) {
  asm("v_mfma_f32_16x16x32_bf16 %0, %1, %2, %0" : "+v"(d) : "v"(a), "v"(b));
}

__device__ __forceinline__ void gload16(const void* g, void* l) {
  __builtin_amdgcn_global_load_lds(
      (__attribute__((address_space(1))) void*)const_cast<void*>(g),
      (__attribute__((address_space(3))) void*)l, 16, 0, 0);
}

// ---------------- f32 -> bf16 convert (linear layout) ----------------
__global__ __launch_bounds__(256) void cvt_bf16(const float* __restrict__ in,
                                                short* __restrict__ out, int n8) {
  int i = blockIdx.x * 256 + threadIdx.x;
  if (i >= n8) return;
  const float4* p = (const float4*)in + (size_t)i * 2;
  float4 a = p[0], b = p[1];
  s16x8 o;
  o[0] = f2bf(a.x); o[1] = f2bf(a.y); o[2] = f2bf(a.z); o[3] = f2bf(a.w);
  o[4] = f2bf(b.x); o[5] = f2bf(b.y); o[6] = f2bf(b.z); o[7] = f2bf(b.w);
  *((s16x8*)out + i) = o;
}

// ---------------- GEMM: C[M][N] = A[M][K] * B[N][K]^T + bias ----------------
__global__ __launch_bounds__(256) void gemm_bt_bias(
    const short* __restrict__ A, const short* __restrict__ B,
    const float* __restrict__ bias, float* __restrict__ C,
    int M, int N, int K) {
  __shared__ __align__(16) short As[128 * 64];
  __shared__ __align__(16) short Bs[128 * 64];
  const int t = threadIdx.x;
  const int l = t & 63, w = t >> 6;
  const int wr = w >> 1, wc = w & 1;
  const int lr = l & 15, lk = l >> 4;
  const int m0 = blockIdx.y * 128, n0 = blockIdx.x * 128;

  f32x4 acc[4][4] = {};

  for (int kt = 0; kt < K; kt += 64) {
    const short* ga = A + (size_t)m0 * K + kt;
    const short* gb = B + (size_t)n0 * K + kt;
#pragma unroll
    for (int i = 0; i < 4; ++i) {
      int j = i * 256 + t;                       // 16B chunk id, 0..1023
      int lbase = (i * 256 + (t & ~63)) << 4;    // wave-uniform LDS byte base
      gload16(ga + (size_t)(j >> 3) * K + ((j & 7) << 3), (char*)As + lbase);
      gload16(gb + (size_t)(j >> 3) * K + ((j & 7) << 3), (char*)Bs + lbase);
    }
    __syncthreads();
#pragma unroll
    for (int ks = 0; ks < 2; ++ks) {
      s16x8 af[4], bg[4];
#pragma unroll
      for (int i = 0; i < 4; ++i) {
        af[i] = *(const s16x8*)(As + (wr * 64 + i * 16 + lr) * 64 + ks * 32 + lk * 8);
        bg[i] = *(const s16x8*)(Bs + (wc * 64 + i * 16 + lr) * 64 + ks * 32 + lk * 8);
      }
#pragma unroll
      for (int mi = 0; mi < 4; ++mi)
#pragma unroll
        for (int ni = 0; ni < 4; ++ni)
          mfma16(acc[mi][ni], af[mi], bg[ni]);
    }
    __syncthreads();
  }
#pragma unroll
  for (int mi = 0; mi < 4; ++mi) {
    int row = m0 + wr * 64 + mi * 16 + lk * 4;
#pragma unroll
    for (int ni = 0; ni < 4; ++ni) {
      int col = n0 + wc * 64 + ni * 16 + lr;
      float bv = bias[col];
#pragma unroll
      for (int r = 0; r < 4; ++r)
        C[(size_t)(row + r) * N + col] = acc[mi][ni][r] + bv;
    }
  }
}

// ---------------- RoPE + split + layout (K/Vt pre-swizzled in global) ----------------
__global__ __launch_bounds__(256) void rope_split(
    const float* __restrict__ qkv, const float* __restrict__ pe,
    short* __restrict__ qws, short* __restrict__ kws, short* __restrict__ vtws) {
  const int s = blockIdx.x;
  const int t = threadIdx.x;
  const float* row = qkv + (size_t)s * 2560;
  const float* per = pe + (size_t)s * 256;
#pragma unroll
  for (int i = 0; i < 5; ++i) {
    int p = t + i * 256;     // pair id 0..1279
    int c0 = p * 2;
    float x0 = row[c0], x1 = row[c0 + 1];
    int d0 = c0 & 127;
    if (c0 < 2048) {         // Q heads
      int hq = c0 >> 7;
      float cc0 = per[d0], cc1 = per[d0 + 1], ss0 = per[128 + d0], ss1 = per[128 + d0 + 1];
      float y0 = (x0 * cc0 + x1 * ss0) * SCALER;
      float y1 = (x1 * cc1 + x0 * ss1) * SCALER;
      size_t off = ((size_t)hq * SQ + s) * DH + d0;
      uint32_t u = (uint32_t)(uint16_t)f2bf(y0) | ((uint32_t)(uint16_t)f2bf(y1) << 16);
      *(uint32_t*)(qws + off) = u;
    } else if (c0 < 2304) {  // K heads
      int hk = (c0 - 2048) >> 7;
      float cc0 = per[d0], cc1 = per[d0 + 1], ss0 = per[128 + d0], ss1 = per[128 + d0 + 1];
      float y0 = x0 * cc0 + x1 * ss0;
      float y1 = x1 * cc1 + x0 * ss1;
      size_t off = (size_t)hk * SQ * DH + (size_t)s * DH + (size_t)((((d0 >> 3) ^ (s & 15)) << 3) + (d0 & 7));
      uint32_t u = (uint32_t)(uint16_t)f2bf(y0) | ((uint32_t)(uint16_t)f2bf(y1) << 16);
      *(uint32_t*)(kws + off) = u;
    } else {                 // V heads, transposed
      int hk = (c0 - 2304) >> 7;
      size_t base = (size_t)hk * DH * SQ;
      int sl = s & 63;
      int d1 = d0 + 1;
      size_t off0 = base + (size_t)d0 * SQ + (s >> 6) * 64 + ((((sl >> 3) ^ (d0 & 7)) << 3) + (sl & 7));
      size_t off1 = base + (size_t)d1 * SQ + (s >> 6) * 64 + ((((sl >> 3) ^ (d1 & 7)) << 3) + (sl & 7));
      vtws[off0] = f2bf(x0);
      vtws[off1] = f2bf(x1);
    }
  }
}

// ---------------- Flash attention ----------------
__global__ __launch_bounds__(256) void attn_fwd(
    const short* __restrict__ qws, const short* __restrict__ kws,
    const short* __restrict__ vtws, short* __restrict__ attnws) {
  __shared__ __align__(16) short Ks[64 * 128];   // [krow][d], slots swizzled
  __shared__ __align__(16) short Vt[128 * 64];   // [d][kcol], slots swizzled
  __shared__ __align__(16) short Ps[4][32 * 72]; // per-wave P, row pad 72

  const int bx = blockIdx.x;
  const int h = bx & 15, qb = bx >> 4;
  const int hk = h >> 3;
  const int t = threadIdx.x, l = t & 63, w = t >> 6;
  const int lr = l & 15, lk = l >> 4;

  s16x8 qf[2][4];
  {
    const short* qbase = qws + ((size_t)h * SQ + (size_t)qb * 128 + w * 32) * DH;
#pragma unroll
    for (int mt = 0; mt < 2; ++mt)
#pragma unroll
      for (int kd = 0; kd < 4; ++kd)
        qf[mt][kd] = *(const s16x8*)(qbase + (size_t)(mt * 16 + lr) * DH + kd * 32 + lk * 8);
  }

  f32x4 o[2][8] = {};
  f32x4 m_[2], l_[2];
#pragma unroll
  for (int mt = 0; mt < 2; ++mt)
#pragma unroll
    for (int r = 0; r < 4; ++r) { m_[mt][r] = -1e30f; l_[mt][r] = 0.f; }

  const int kbmax = 2 * qb + 1;
  const int wrow_min = qb * 128 + w * 32;
  const int wrow_max = wrow_min + 31;

  for (int kb = 0; kb <= kbmax; ++kb) {
    {  // stage K (16KB) + Vt (16KB), pre-swizzled in global -> linear copy
      const short* gk = kws + (size_t)hk * SQ * DH + (size_t)kb * 64 * DH;
      const short* gv = vtws + (size_t)hk * DH * SQ + (size_t)kb * 64;
#pragma unroll
      for (int i = 0; i < 4; ++i) {
        int j = i * 256 + t;
        int lbase = (i * 256 + (t & ~63)) << 4;
        gload16(gk + (size_t)(j >> 4) * DH + ((j & 15) << 3), (char*)Ks + lbase);
        gload16(gv + (size_t)(j >> 3) * SQ + ((j & 7) << 3), (char*)Vt + lbase);
      }
    }
    __syncthreads();
    bool active = (kb * 64) <= wrow_max;
    if (active) {
      // ---- S = Q K^T ----
      f32x4 sc_[2][4] = {};
#pragma unroll
      for (int kd = 0; kd < 4; ++kd) {
        s16x8 bfr[4];
#pragma unroll
        for (int nt = 0; nt < 4; ++nt) {
          int krow = nt * 16 + lr;
          int slot = (kd * 4 + lk) ^ lr;
          bfr[nt] = *(const s16x8*)(Ks + krow * 128 + slot * 8);
        }
#pragma unroll
        for (int mt = 0; mt < 2; ++mt)
#pragma unroll
          for (int nt = 0; nt < 4; ++nt)
            mfma16(sc_[mt][nt], qf[mt][kd], bfr[nt]);
      }
      // ---- causal mask (gate on wave's MIN row: any col beyond it needs masking) ----
      if (kb * 64 + 63 > wrow_min) {
#pragma unroll
        for (int mt = 0; mt < 2; ++mt)
#pragma unroll
          for (int nt = 0; nt < 4; ++nt)
#pragma unroll
            for (int r = 0; r < 4; ++r) {
              int col = kb * 64 + nt * 16 + lr;
              int qrow = wrow_min + mt * 16 + lk * 4 + r;
              if (col > qrow) sc_[mt][nt][r] = -1e30f;
            }
      }
      // ---- online softmax (wave-parallel, 16-lane-group reductions) ----
#pragma unroll
      for (int mt = 0; mt < 2; ++mt) {
        f32x4 rm;
#pragma unroll
        for (int r = 0; r < 4; ++r)
          rm[r] = fmaxf(fmaxf(sc_[mt][0][r], sc_[mt][1][r]), fmaxf(sc_[mt][2][r], sc_[mt][3][r]));
#pragma unroll
        for (int off = 1; off < 16; off <<= 1)
#pragma unroll
          for (int r = 0; r < 4; ++r) rm[r] = fmaxf(rm[r], __shfl_xor(rm[r], off, 16));
        f32x4 mn, scl, rs;
#pragma unroll
        for (int r = 0; r < 4; ++r) {
          mn[r] = fmaxf(m_[mt][r], rm[r]);
          scl[r] = __expf(m_[mt][r] - mn[r]);
          rs[r] = 0.f;
        }
#pragma unroll
        for (int nt = 0; nt < 4; ++nt)
#pragma unroll
          for (int r = 0; r < 4; ++r) {
            sc_[mt][nt][r] = __expf(sc_[mt][nt][r] - mn[r]);
            rs[r] += sc_[mt][nt][r];
          }
#pragma unroll
        for (int off = 1; off < 16; off <<= 1)
#pragma unroll
          for (int r = 0; r < 4; ++r) rs[r] += __shfl_xor(rs[r], off, 16);
#pragma unroll
        for (int r = 0; r < 4; ++r) {
          l_[mt][r] = l_[mt][r] * scl[r] + rs[r];
          m_[mt][r] = mn[r];
        }
#pragma unroll
        for (int dt = 0; dt < 8; ++dt)
#pragma unroll
          for (int r = 0; r < 4; ++r) o[mt][dt][r] *= scl[r];
        short* ps = (short*)Ps[w];
#pragma unroll
        for (int nt = 0; nt < 4; ++nt)
#pragma unroll
          for (int r = 0; r < 4; ++r)
            ps[(mt * 16 + lk * 4 + r) * 72 + nt * 16 + lr] = f2bf(sc_[mt][nt][r]);
      }
      // ---- O += P V ----
      const short* ps = (const short*)Ps[w];
#pragma unroll
      for (int kp = 0; kp < 2; ++kp) {
        s16x8 pa[2];
#pragma unroll
        for (int mt = 0; mt < 2; ++mt)
          pa[mt] = *(const s16x8*)(ps + (mt * 16 + lr) * 72 + kp * 32 + lk * 8);
#pragma unroll
        for (int dt = 0; dt < 8; ++dt) {
          int drow = dt * 16 + lr;
          int slot = (kp * 4 + lk) ^ (lr & 7);
          s16x8 vb = *(const s16x8*)(Vt + drow * 64 + slot * 8);
#pragma unroll
          for (int mt = 0; mt < 2; ++mt)
            mfma16(o[mt][dt], pa[mt], vb);
        }
      }
    }
    __syncthreads();
  }
  // ---- epilogue ----
#pragma unroll
  for (int mt = 0; mt < 2; ++mt) {
    int srow = qb * 128 + w * 32 + mt * 16 + lk * 4;
#pragma unroll
    for (int dt = 0; dt < 8; ++dt) {
      int col = h * DH + dt * 16 + lr;
#pragma unroll
      for (int r = 0; r < 4; ++r) {
        float val = o[mt][dt][r] / l_[mt][r];
        attnws[(size_t)(srow + r) * 2048 + col] = f2bf(val);
      }
    }
  }
}

extern "C" void kernel_launch(void* const* d_in, const int* in_sizes, int n_in,
                              void* d_out, int out_size, void* d_ws, size_t ws_size,
                              hipStream_t stream) {
  (void)in_sizes; (void)n_in; (void)out_size; (void)ws_size;
  const float* x     = (const float*)d_in[0];
  const float* w_qkv = (const float*)d_in[2];
  const float* b_qkv = (const float*)d_in[3];
  const float* w_o   = (const float*)d_in[4];
  const float* b_o   = (const float*)d_in[5];
  const float* pe    = (const float*)d_in[6];
  float* out = (float*)d_out;

  short* xb     = (short*)d_ws;                        // bf16 [2048][2048]
  short* wqkvb  = xb + (size_t)2048 * 2048;            // bf16 [2560][2048]
  short* wob    = wqkvb + (size_t)2560 * 2048;         // bf16 [2048][2048]
  float* qkv    = (float*)(wob + (size_t)2048 * 2048); // f32  [2048][2560]
  short* qws    = (short*)(qkv + (size_t)2048 * 2560); // bf16 [16][2048][128]
  short* kws    = qws + (size_t)16 * 2048 * 128;       // bf16 [2][2048][128] swizzled
  short* vtws   = kws + (size_t)2 * 2048 * 128;        // bf16 [2][128][2048] swizzled
  short* attnws = xb;                                  // reuse xb after QKV GEMM

  cvt_bf16<<<2048, 256, 0, stream>>>(x, xb, 2048 * 2048 / 8);
  cvt_bf16<<<2560, 256, 0, stream>>>(w_qkv, wqkvb, 2560 * 2048 / 8);
  cvt_bf16<<<2048, 256, 0, stream>>>(w_o, wob, 2048 * 2048 / 8);
  gemm_bt_bias<<<dim3(2560 / 128, 2048 / 128), 256, 0, stream>>>(
      xb, wqkvb, b_qkv, qkv, 2048, 2560, 2048);
  rope_split<<<2048, 256, 0, stream>>>(qkv, pe, qws, kws, vtws);
  attn_fwd<<<256, 256, 0, stream>>>(qws, kws, vtws, attnws);
  gemm_bt_bias<<<dim3(2048 / 128, 2048 / 128), 256, 0, stream>>>(
      attnws, wob, b_o, out, 2048, 2048, 2048);
}

// Round 3
// 182.046 us; speedup vs baseline: 1.1712x; 1.1712x over previous
//
#include <hip/hip_runtime.h>
#include <stdint.h>

#define SQ 2048
#define DH 128
#define SCALER 0.08838834764831845f  // 1/sqrt(128)

typedef float f32x4 __attribute__((ext_vector_type(4)));
typedef short s16x8 __attribute__((ext_vector_type(8)));

__device__ __forceinline__ short f2bf(float f) {
  uint32_t x = __float_as_uint(f);
  uint32_t r = (x + 0x7fffu + ((x >> 16) & 1u)) >> 16;  // RNE
  return (short)(r & 0xffffu);
}

__device__ __forceinline__ void mfma16(f32x4& d, s16x8 a, s16x8 b) {
  asm("v_mfma_f32_16x16x32_bf16 %0, %1, %2, %0" : "+v"(d) : "v"(a), "v"(b));
}

__device__ __forceinline__ void gload16(const void* g, void* l) {
  __builtin_amdgcn_global_load_lds(
      (__attribute__((address_space(1))) void*)const_cast<void*>(g),
      (__attribute__((address_space(3))) void*)l, 16, 0, 0);
}

// ---------------- f32 -> bf16 convert (linear layout) ----------------
__global__ __launch_bounds__(256) void cvt_bf16(const float* __restrict__ in,
                                                short* __restrict__ out, int n8) {
  int i = blockIdx.x * 256 + threadIdx.x;
  if (i >= n8) return;
  const float4* p = (const float4*)in + (size_t)i * 2;
  float4 a = p[0], b = p[1];
  s16x8 o;
  o[0] = f2bf(a.x); o[1] = f2bf(a.y); o[2] = f2bf(a.z); o[3] = f2bf(a.w);
  o[4] = f2bf(b.x); o[5] = f2bf(b.y); o[6] = f2bf(b.z); o[7] = f2bf(b.w);
  *((s16x8*)out + i) = o;
}

// ---------------- GEMM: C[M][N] = A[M][K] * B[N][K]^T + bias ----------------
__global__ __launch_bounds__(256) void gemm_bt_bias(
    const short* __restrict__ A, const short* __restrict__ B,
    const float* __restrict__ bias, float* __restrict__ C,
    int M, int N, int K) {
  __shared__ __align__(16) short As[128 * 64];
  __shared__ __align__(16) short Bs[128 * 64];
  const int t = threadIdx.x;
  const int l = t & 63, w = t >> 6;
  const int wr = w >> 1, wc = w & 1;
  const int lr = l & 15, lk = l >> 4;
  const int m0 = blockIdx.y * 128, n0 = blockIdx.x * 128;

  f32x4 acc[4][4] = {};

  for (int kt = 0; kt < K; kt += 64) {
    const short* ga = A + (size_t)m0 * K + kt;
    const short* gb = B + (size_t)n0 * K + kt;
#pragma unroll
    for (int i = 0; i < 4; ++i) {
      int j = i * 256 + t;                       // 16B chunk id, 0..1023
      int lbase = (i * 256 + (t & ~63)) << 4;    // wave-uniform LDS byte base
      gload16(ga + (size_t)(j >> 3) * K + ((j & 7) << 3), (char*)As + lbase);
      gload16(gb + (size_t)(j >> 3) * K + ((j & 7) << 3), (char*)Bs + lbase);
    }
    __syncthreads();
#pragma unroll
    for (int ks = 0; ks < 2; ++ks) {
      s16x8 af[4], bg[4];
#pragma unroll
      for (int i = 0; i < 4; ++i) {
        af[i] = *(const s16x8*)(As + (wr * 64 + i * 16 + lr) * 64 + ks * 32 + lk * 8);
        bg[i] = *(const s16x8*)(Bs + (wc * 64 + i * 16 + lr) * 64 + ks * 32 + lk * 8);
      }
#pragma unroll
      for (int mi = 0; mi < 4; ++mi)
#pragma unroll
        for (int ni = 0; ni < 4; ++ni)
          mfma16(acc[mi][ni], af[mi], bg[ni]);
    }
    __syncthreads();
  }
#pragma unroll
  for (int mi = 0; mi < 4; ++mi) {
    int row = m0 + wr * 64 + mi * 16 + lk * 4;
#pragma unroll
    for (int ni = 0; ni < 4; ++ni) {
      int col = n0 + wc * 64 + ni * 16 + lr;
      float bv = bias[col];
#pragma unroll
      for (int r = 0; r < 4; ++r)
        C[(size_t)(row + r) * N + col] = acc[mi][ni][r] + bv;
    }
  }
}

// ---------------- RoPE + split + layout (K/Vt pre-swizzled in global) ----------------
__global__ __launch_bounds__(256) void rope_split(
    const float* __restrict__ qkv, const float* __restrict__ pe,
    short* __restrict__ qws, short* __restrict__ kws, short* __restrict__ vtws) {
  const int s = blockIdx.x;
  const int t = threadIdx.x;
  const float* row = qkv + (size_t)s * 2560;
  const float* per = pe + (size_t)s * 256;
#pragma unroll
  for (int i = 0; i < 5; ++i) {
    int p = t + i * 256;     // pair id 0..1279
    int c0 = p * 2;
    float x0 = row[c0], x1 = row[c0 + 1];
    int d0 = c0 & 127;
    if (c0 < 2048) {         // Q heads
      int hq = c0 >> 7;
      float cc0 = per[d0], cc1 = per[d0 + 1], ss0 = per[128 + d0], ss1 = per[128 + d0 + 1];
      float y0 = (x0 * cc0 + x1 * ss0) * SCALER;
      float y1 = (x1 * cc1 + x0 * ss1) * SCALER;
      size_t off = ((size_t)hq * SQ + s) * DH + d0;
      uint32_t u = (uint32_t)(uint16_t)f2bf(y0) | ((uint32_t)(uint16_t)f2bf(y1) << 16);
      *(uint32_t*)(qws + off) = u;
    } else if (c0 < 2304) {  // K heads
      int hk = (c0 - 2048) >> 7;
      float cc0 = per[d0], cc1 = per[d0 + 1], ss0 = per[128 + d0], ss1 = per[128 + d0 + 1];
      float y0 = x0 * cc0 + x1 * ss0;
      float y1 = x1 * cc1 + x0 * ss1;
      size_t off = (size_t)hk * SQ * DH + (size_t)s * DH + (size_t)((((d0 >> 3) ^ (s & 15)) << 3) + (d0 & 7));
      uint32_t u = (uint32_t)(uint16_t)f2bf(y0) | ((uint32_t)(uint16_t)f2bf(y1) << 16);
      *(uint32_t*)(kws + off) = u;
    } else {                 // V heads, transposed
      int hk = (c0 - 2304) >> 7;
      size_t base = (size_t)hk * DH * SQ;
      int sl = s & 63;
      int d1 = d0 + 1;
      size_t off0 = base + (size_t)d0 * SQ + (s >> 6) * 64 + ((((sl >> 3) ^ (d0 & 7)) << 3) + (sl & 7));
      size_t off1 = base + (size_t)d1 * SQ + (s >> 6) * 64 + ((((sl >> 3) ^ (d1 & 7)) << 3) + (sl & 7));
      vtws[off0] = f2bf(x0);
      vtws[off1] = f2bf(x1);
    }
  }
}

// ---------------- Flash attention ----------------
// 512 WGs: (h, qb) with qb descending. 4 waves x 16 q-rows (QBLK=64).
// KBLK=64, double-buffered K/V staging (2-phase pipeline).
__global__ __launch_bounds__(256) void attn_fwd(
    const short* __restrict__ qws, const short* __restrict__ kws,
    const short* __restrict__ vtws, short* __restrict__ attnws) {
  __shared__ __align__(16) short Ks[2][64 * 128];  // [buf][krow][d], slots swizzled
  __shared__ __align__(16) short Vt[2][128 * 64];  // [buf][d][kcol], slots swizzled
  __shared__ __align__(16) short Ps[4][16 * 72];   // per-wave P, row pad 72

  const int bx = blockIdx.x;
  const int h = bx & 15;
  const int qb = 31 - (bx >> 4);    // descending qb: longest blocks dispatch first
  const int hk = h >> 3;
  const int t = threadIdx.x, l = t & 63, w = t >> 6;
  const int lr = l & 15, lk = l >> 4;

  // Q fragments (rows qb*64 + w*16 + lr)
  s16x8 qf[4];
  {
    const short* qbase = qws + ((size_t)h * SQ + (size_t)qb * 64 + w * 16) * DH;
#pragma unroll
    for (int kd = 0; kd < 4; ++kd)
      qf[kd] = *(const s16x8*)(qbase + (size_t)lr * DH + kd * 32 + lk * 8);
  }

  f32x4 o[8] = {};
  f32x4 m_, l_;
#pragma unroll
  for (int r = 0; r < 4; ++r) { m_[r] = -1e30f; l_[r] = 0.f; }

  const short* gkh = kws + (size_t)hk * SQ * DH;
  const short* gvh = vtws + (size_t)hk * DH * SQ;

#define STAGE(buf, kb)                                                          \
  {                                                                             \
    const short* gk = gkh + (size_t)(kb)*64 * DH;                               \
    const short* gv = gvh + (size_t)(kb)*64;                                    \
    _Pragma("unroll") for (int i = 0; i < 4; ++i) {                             \
      int j = i * 256 + t;                                                      \
      int lbase = (i * 256 + (t & ~63)) << 4;                                   \
      gload16(gk + (size_t)(j >> 4) * DH + ((j & 15) << 3),                     \
              (char*)Ks[buf] + lbase);                                          \
      gload16(gv + (size_t)(j >> 3) * SQ + ((j & 7) << 3),                      \
              (char*)Vt[buf] + lbase);                                          \
    }                                                                           \
  }

  STAGE(0, 0);
  __syncthreads();  // implicit vmcnt(0) drain

  const int row_base = w * 16;  // local within the 64-row q-block

  for (int kb = 0; kb <= qb; ++kb) {
    const int cur = kb & 1;
    if (kb < qb) STAGE(cur ^ 1, kb + 1);  // prefetch next tile under compute

    // ---- S = Q K^T ----
    f32x4 sc_[4] = {};
#pragma unroll
    for (int kd = 0; kd < 4; ++kd) {
      s16x8 bfr[4];
#pragma unroll
      for (int nt = 0; nt < 4; ++nt) {
        int krow = nt * 16 + lr;
        int slot = (kd * 4 + lk) ^ lr;
        bfr[nt] = *(const s16x8*)(Ks[cur] + krow * 128 + slot * 8);
      }
#pragma unroll
      for (int nt = 0; nt < 4; ++nt)
        mfma16(sc_[nt], qf[kd], bfr[nt]);
    }
    // ---- causal mask (only the diagonal k-block needs it) ----
    if (kb == qb) {
#pragma unroll
      for (int nt = 0; nt < 4; ++nt)
#pragma unroll
        for (int r = 0; r < 4; ++r) {
          int col = nt * 16 + lr;
          int row = row_base + lk * 4 + r;
          if (col > row) sc_[nt][r] = -1e30f;
        }
    }
    // ---- online softmax (wave-parallel, 16-lane-group reductions) ----
    {
      f32x4 rm;
#pragma unroll
      for (int r = 0; r < 4; ++r)
        rm[r] = fmaxf(fmaxf(sc_[0][r], sc_[1][r]), fmaxf(sc_[2][r], sc_[3][r]));
#pragma unroll
      for (int off = 1; off < 16; off <<= 1)
#pragma unroll
        for (int r = 0; r < 4; ++r) rm[r] = fmaxf(rm[r], __shfl_xor(rm[r], off, 16));
      f32x4 mn, scl, rs;
#pragma unroll
      for (int r = 0; r < 4; ++r) {
        mn[r] = fmaxf(m_[r], rm[r]);
        scl[r] = __expf(m_[r] - mn[r]);
        rs[r] = 0.f;
      }
#pragma unroll
      for (int nt = 0; nt < 4; ++nt)
#pragma unroll
        for (int r = 0; r < 4; ++r) {
          sc_[nt][r] = __expf(sc_[nt][r] - mn[r]);
          rs[r] += sc_[nt][r];
        }
#pragma unroll
      for (int off = 1; off < 16; off <<= 1)
#pragma unroll
        for (int r = 0; r < 4; ++r) rs[r] += __shfl_xor(rs[r], off, 16);
#pragma unroll
      for (int r = 0; r < 4; ++r) {
        l_[r] = l_[r] * scl[r] + rs[r];
        m_[r] = mn[r];
      }
#pragma unroll
      for (int dt = 0; dt < 8; ++dt)
#pragma unroll
        for (int r = 0; r < 4; ++r) o[dt][r] *= scl[r];
      short* ps = (short*)Ps[w];
#pragma unroll
      for (int nt = 0; nt < 4; ++nt)
#pragma unroll
        for (int r = 0; r < 4; ++r)
          ps[(lk * 4 + r) * 72 + nt * 16 + lr] = f2bf(sc_[nt][r]);
    }
    // ---- O += P V ----
    {
      const short* ps = (const short*)Ps[w];
#pragma unroll
      for (int kp = 0; kp < 2; ++kp) {
        s16x8 pa = *(const s16x8*)(ps + lr * 72 + kp * 32 + lk * 8);
#pragma unroll
        for (int dt = 0; dt < 8; ++dt) {
          int drow = dt * 16 + lr;
          int slot = (kp * 4 + lk) ^ (lr & 7);
          s16x8 vb = *(const s16x8*)(Vt[cur] + drow * 64 + slot * 8);
          mfma16(o[dt], pa, vb);
        }
      }
    }
    __syncthreads();  // drains next-tile loads; guards buf reuse
  }
#undef STAGE

  // ---- epilogue: O /= l, write bf16 [s][h*128+d] linear ----
#pragma unroll
  for (int dt = 0; dt < 8; ++dt) {
    int col = h * DH + dt * 16 + lr;
#pragma unroll
    for (int r = 0; r < 4; ++r) {
      int srow = qb * 64 + w * 16 + lk * 4 + r;
      float val = o[dt][r] / l_[r];
      attnws[(size_t)srow * 2048 + col] = f2bf(val);
    }
  }
}

extern "C" void kernel_launch(void* const* d_in, const int* in_sizes, int n_in,
                              void* d_out, int out_size, void* d_ws, size_t ws_size,
                              hipStream_t stream) {
  (void)in_sizes; (void)n_in; (void)out_size; (void)ws_size;
  const float* x     = (const float*)d_in[0];
  const float* w_qkv = (const float*)d_in[2];
  const float* b_qkv = (const float*)d_in[3];
  const float* w_o   = (const float*)d_in[4];
  const float* b_o   = (const float*)d_in[5];
  const float* pe    = (const float*)d_in[6];
  float* out = (float*)d_out;

  short* xb     = (short*)d_ws;                        // bf16 [2048][2048]
  short* wqkvb  = xb + (size_t)2048 * 2048;            // bf16 [2560][2048]
  short* wob    = wqkvb + (size_t)2560 * 2048;         // bf16 [2048][2048]
  float* qkv    = (float*)(wob + (size_t)2048 * 2048); // f32  [2048][2560]
  short* qws    = (short*)(qkv + (size_t)2048 * 2560); // bf16 [16][2048][128]
  short* kws    = qws + (size_t)16 * 2048 * 128;       // bf16 [2][2048][128] swizzled
  short* vtws   = kws + (size_t)2 * 2048 * 128;        // bf16 [2][128][2048] swizzled
  short* attnws = xb;                                  // reuse xb after QKV GEMM

  cvt_bf16<<<2048, 256, 0, stream>>>(x, xb, 2048 * 2048 / 8);
  cvt_bf16<<<2560, 256, 0, stream>>>(w_qkv, wqkvb, 2560 * 2048 / 8);
  cvt_bf16<<<2048, 256, 0, stream>>>(w_o, wob, 2048 * 2048 / 8);
  gemm_bt_bias<<<dim3(2560 / 128, 2048 / 128), 256, 0, stream>>>(
      xb, wqkvb, b_qkv, qkv, 2048, 2560, 2048);
  rope_split<<<2048, 256, 0, stream>>>(qkv, pe, qws, kws, vtws);
  attn_fwd<<<512, 256, 0, stream>>>(qws, kws, vtws, attnws);
  gemm_bt_bias<<<dim3(2048 / 128, 2048 / 128), 256, 0, stream>>>(
      attnws, wob, b_o, out, 2048, 2048, 2048);
}